// Round 1
// baseline (52.599 us; speedup 1.0000x reference)
//
#include <hip/hip_runtime.h>

// Quanv2D surrogate:
// out[b, c*4+e, h, w] = 0.1 * precision * sin^2(0.5 * <patch(b,c,h,w), weight[c*4+e]>)
//                     = 0.05 * precision * (1 - cos(<patch, weight_row>))
// patch k-order: (h,w), (h,w+1), (h+1,w), (h+1,w+1)
// Shapes: x[64,4,224,224] f32, weight[16,4] f32, precision int scalar,
//         out[64,16,223,223] f32.

#define IW 224
#define IH 224
#define OW 223
#define OH 223
#define C_IN 4
#define E_EXT 4

__global__ __launch_bounds__(256) void quanv2d_kernel(
    const float* __restrict__ x,      // [B,4,224,224]
    const float* __restrict__ wt,     // [16,4]
    const int*   __restrict__ prec,   // [1]
    float*       __restrict__ out)    // [B,16,223,223]
{
    const int w = blockIdx.x * blockDim.x + threadIdx.x;   // output col
    if (w >= OW) return;
    const int h  = blockIdx.y;                             // output row
    const int bc = blockIdx.z;                             // b*4 + c
    const int b  = bc >> 2;
    const int c  = bc & 3;

    // patch loads (coalesced along w; +1 offsets are L1 hits)
    const float* xp = x + (bc * IH + h) * IW + w;
    const float p0 = xp[0];
    const float p1 = xp[1];
    const float p2 = xp[IW];
    const float p3 = xp[IW + 1];

    const float scale = 0.05f * (float)(*prec);            // uniform -> SGPR

    // out channel base: oc = c*4 + e
    float* op = out + ((b * (C_IN * E_EXT) + c * E_EXT) * OH + h) * OW + w;
    const float* wr = wt + (c * E_EXT) * 4;                // uniform -> s_load

#pragma unroll
    for (int e = 0; e < E_EXT; ++e) {
        const float angle = p0 * wr[e * 4 + 0] + p1 * wr[e * 4 + 1]
                          + p2 * wr[e * 4 + 2] + p3 * wr[e * 4 + 3];
        op[e * (OH * OW)] = scale * (1.0f - __cosf(angle));
    }
}

extern "C" void kernel_launch(void* const* d_in, const int* in_sizes, int n_in,
                              void* d_out, int out_size, void* d_ws, size_t ws_size,
                              hipStream_t stream)
{
    const float* x    = (const float*)d_in[0];
    const float* wt   = (const float*)d_in[1];
    const int*   prec = (const int*)d_in[2];
    float*       out  = (float*)d_out;

    const int B = 64;
    dim3 block(256, 1, 1);
    dim3 grid((OW + 255) / 256, OH, B * C_IN);   // (1, 223, 256)
    quanv2d_kernel<<<grid, block, 0, stream>>>(x, wt, prec, out);
}